// Round 1
// baseline (171.062 us; speedup 1.0000x reference)
//
#include <hip/hip_runtime.h>
#include <hip/hip_bf16.h>

#define BT 128   // B*T
#define NN 256   // nodes
#define FF 128   // features
#define HH 4     // heads
#define DD 32    // head dim

__device__ __forceinline__ float lrelu(float x) { return x > 0.f ? x : 0.2f * x; }
__device__ __forceinline__ float elu1(float x) { return x > 0.f ? x : (__expf(x) - 1.f); }

// One block = one (bt, 64-row tile). 256 threads: thread (row = tid&63, head = tid>>6)
// computes the 32-wide head slice of one output row, plus the s1/s2 attention scores.
__global__ __launch_bounds__(256) void gemm_scores(
    const float* __restrict__ x, const float* __restrict__ W,
    const float* __restrict__ a, float* __restrict__ Wh,
    float* __restrict__ s1, float* __restrict__ s2) {
  __shared__ float ws[FF][FF];      // 64 KB
  __shared__ float xs[64][FF + 1];  // 33 KB, +1 pad -> xs[lane][k] is 2-way (free)
  const int bt = blockIdx.x >> 2;
  const int rbase = (blockIdx.x & 3) * 64;
  const int tid = threadIdx.x;

  for (int idx = tid * 4; idx < FF * FF; idx += 1024) {
    *(float4*)&ws[idx >> 7][idx & 127] = *(const float4*)&W[idx];
  }
  const float* xp = x + ((size_t)bt * NN + rbase) * FF;
  for (int idx = tid * 4; idx < 64 * FF; idx += 1024) {
    float4 v = *(const float4*)&xp[idx];
    int r = idx >> 7, c = idx & 127;
    xs[r][c] = v.x; xs[r][c + 1] = v.y; xs[r][c + 2] = v.z; xs[r][c + 3] = v.w;
  }
  __syncthreads();

  const int row = tid & 63;
  const int hg = tid >> 6;
  float acc[DD] = {};
  #pragma unroll 4
  for (int k = 0; k < FF; ++k) {
    float xv = xs[row][k];
    #pragma unroll
    for (int c4 = 0; c4 < DD; c4 += 4) {
      float4 w4 = *(float4*)&ws[k][hg * DD + c4];  // wave-uniform -> broadcast
      acc[c4]     = fmaf(xv, w4.x, acc[c4]);
      acc[c4 + 1] = fmaf(xv, w4.y, acc[c4 + 1]);
      acc[c4 + 2] = fmaf(xv, w4.z, acc[c4 + 2]);
      acc[c4 + 3] = fmaf(xv, w4.w, acc[c4 + 3]);
    }
  }

  // epilogue: attention scores s1 = Wh_head . a[:32], s2 = Wh_head . a[32:]
  float s1v = 0.f, s2v = 0.f;
  #pragma unroll
  for (int c = 0; c < DD; ++c) {
    s1v = fmaf(acc[c], a[c], s1v);
    s2v = fmaf(acc[c], a[DD + c], s2v);
  }
  float* whp = Wh + ((size_t)bt * NN + rbase + row) * FF + hg * DD;
  #pragma unroll
  for (int c4 = 0; c4 < DD; c4 += 4) {
    *(float4*)&whp[c4] = make_float4(acc[c4], acc[c4 + 1], acc[c4 + 2], acc[c4 + 3]);
  }
  const int sidx = (bt * HH + hg) * NN + rbase + row;
  s1[sidx] = s1v;
  s2[sidx] = s2v;
}

// One block = one (bt, head). 256 threads, thread = query node i.
// Single-pass softmax: row max factors to lrelu(s1_i + max_valid_j s2_j).
// Fused: PV accumulation + residual + ELU, written in-place-safe per head column block.
__global__ __launch_bounds__(256) void attn_fused(
    const float* __restrict__ Wh, const float* __restrict__ s1g,
    const float* __restrict__ s2g, const int* __restrict__ mask,
    const float* __restrict__ xres, float* __restrict__ xout) {
  __shared__ float whs[NN][DD];  // 32 KB; inner reads are wave-uniform (broadcast)
  __shared__ float s2s[NN];
  __shared__ float red[NN];
  __shared__ int valid[NN];
  const int bt = blockIdx.x >> 2;
  const int h = blockIdx.x & 3;
  const int tid = threadIdx.x;  // query node i

  const float* whp = Wh + (size_t)bt * NN * FF + h * DD;
  for (int idx = tid; idx < NN * 8; idx += 256) {
    int j = idx >> 3, dg = idx & 7;
    *(float4*)&whs[j][dg * 4] = *(const float4*)&whp[(size_t)j * FF + dg * 4];
  }
  const int mv = mask[bt * NN + tid] > 0;
  valid[tid] = mv;
  const float s2v = s2g[(bt * HH + h) * NN + tid];
  s2s[tid] = s2v;
  red[tid] = mv ? s2v : -1e30f;
  __syncthreads();
  for (int off = 128; off > 0; off >>= 1) {
    if (tid < off) red[tid] = fmaxf(red[tid], red[tid + off]);
    __syncthreads();
  }
  const float s2max = red[0];

  const float s1v = s1g[(bt * HH + h) * NN + tid];
  float acc[DD] = {};
  float denom = 0.f;
  if (mv) {
    const float emax = lrelu(s1v + s2max);
    for (int j = 0; j < NN; ++j) {
      if (valid[j]) {  // wave-uniform branch: masked j skipped for free
        float p = __expf(lrelu(s1v + s2s[j]) - emax);
        denom += p;
        #pragma unroll
        for (int dg = 0; dg < 8; ++dg) {
          float4 w = *(float4*)&whs[j][dg * 4];  // broadcast
          acc[dg * 4]     += p * w.x;
          acc[dg * 4 + 1] += p * w.y;
          acc[dg * 4 + 2] += p * w.z;
          acc[dg * 4 + 3] += p * w.w;
        }
      }
    }
  }
  const float inv = mv ? (1.f / denom) : 0.f;  // denom>0 when mv (j=i is valid)

  const float* xr = xres + ((size_t)bt * NN + tid) * FF + h * DD;
  float* xo = xout + ((size_t)bt * NN + tid) * FF + h * DD;
  #pragma unroll
  for (int dg = 0; dg < 8; ++dg) {
    float4 r = *(const float4*)&xr[dg * 4];
    float4 o;
    o.x = elu1(r.x + acc[dg * 4]     * inv);
    o.y = elu1(r.y + acc[dg * 4 + 1] * inv);
    o.z = elu1(r.z + acc[dg * 4 + 2] * inv);
    o.w = elu1(r.w + acc[dg * 4 + 3] * inv);
    *(float4*)&xo[dg * 4] = o;
  }
}

// One wave per row (128 features, 2 per lane), 4 rows per block.
__global__ __launch_bounds__(256) void layernorm_mask(
    const float* __restrict__ x, const int* __restrict__ mask,
    const float* __restrict__ gamma, const float* __restrict__ beta,
    float* __restrict__ out) {
  const int lane = threadIdx.x & 63;
  const size_t row = (size_t)blockIdx.x * 4 + (threadIdx.x >> 6);
  const float* xp = x + row * FF;
  float2 v = *(const float2*)&xp[lane * 2];
  float sum = v.x + v.y;
  float sq = v.x * v.x + v.y * v.y;
  #pragma unroll
  for (int off = 32; off > 0; off >>= 1) {
    sum += __shfl_xor(sum, off, 64);
    sq  += __shfl_xor(sq, off, 64);
  }
  const float mu = sum * (1.f / FF);
  const float var = sq * (1.f / FF) - mu * mu;
  const float rstd = rsqrtf(var + 1e-5f);
  const float m = mask[row] > 0 ? 1.f : 0.f;
  float2 g = *(const float2*)&gamma[lane * 2];
  float2 b = *(const float2*)&beta[lane * 2];
  float2 o;
  o.x = ((v.x - mu) * rstd * g.x + b.x) * m;
  o.y = ((v.y - mu) * rstd * g.y + b.y) * m;
  *(float2*)&out[row * FF + lane * 2] = o;
}

extern "C" void kernel_launch(void* const* d_in, const int* in_sizes, int n_in,
                              void* d_out, int out_size, void* d_ws, size_t ws_size,
                              hipStream_t stream) {
  const float* xin   = (const float*)d_in[0];  // organ_states (BT, N, F)
  const int*   mask  = (const int*)d_in[1];    // organ_mask (BT, N)
  const float* W0    = (const float*)d_in[2];
  const float* a0    = (const float*)d_in[3];
  const float* W1    = (const float*)d_in[4];
  const float* a1    = (const float*)d_in[5];
  const float* gamma = (const float*)d_in[6];
  const float* beta  = (const float*)d_in[7];

  float* x_cur = (float*)d_ws;                        // 16.78 MB
  float* Wh    = x_cur + (size_t)BT * NN * FF;        // 16.78 MB
  float* s1    = Wh + (size_t)BT * NN * FF;           // 0.5 MB
  float* s2    = s1 + (size_t)BT * HH * NN;           // 0.5 MB

  // layer 0 (x = organ_states)
  gemm_scores<<<BT * 4, 256, 0, stream>>>(xin, W0, a0, Wh, s1, s2);
  attn_fused<<<BT * HH, 256, 0, stream>>>(Wh, s1, s2, mask, xin, x_cur);
  // layer 1 (x = x_cur, updated in place by attn epilogue)
  gemm_scores<<<BT * 4, 256, 0, stream>>>(x_cur, W1, a1, Wh, s1, s2);
  attn_fused<<<BT * HH, 256, 0, stream>>>(Wh, s1, s2, mask, x_cur, x_cur);
  // layernorm + mask -> out
  layernorm_mask<<<BT * NN / 4, 256, 0, stream>>>(x_cur, mask, gamma, beta, (float*)d_out);
}

// Round 2
// 73.477 us; speedup vs baseline: 2.3281x; 2.3281x over previous
//
#include <hip/hip_runtime.h>
#include <hip/hip_bf16.h>

#define BT 128   // B*T
#define NN 256   // nodes
#define FF 128   // features
#define HH 4     // heads
#define DD 32    // head dim
#define XK 136   // LDS k-stride (bf16) for gemm tiles: 272B = 17*16, 16B-aligned, 8 bank-groups
#define WTS 264  // LDS j-stride (bf16) for whT: 528B = 33*16

typedef __attribute__((ext_vector_type(8))) short bf16x8;
typedef __attribute__((ext_vector_type(4))) float f32x4;
typedef unsigned int uint;
typedef unsigned short ushort;

__device__ __forceinline__ float lrelu(float x) { return x > 0.f ? x : 0.2f * x; }
__device__ __forceinline__ float elu1(float x) { return x > 0.f ? x : (__expf(x) - 1.f); }
__device__ __forceinline__ ushort f2bf(float f) {
  union { float f; uint u; } v; v.f = f;
  uint r = v.u + 0x7fffu + ((v.u >> 16) & 1u);  // RNE
  return (ushort)(r >> 16);
}
__device__ __forceinline__ float bf2f(ushort u) {
  union { uint u; float f; } v; v.u = ((uint)u) << 16; return v.f;
}
__device__ __forceinline__ uint pk2(float a, float b) {
  return (uint)f2bf(a) | ((uint)f2bf(b) << 16);
}

// Block = (bt, row-half). 4 waves, each computes 64x64 of the 128x128 tile.
// Output: WhT[bt][f][n] bf16 (transposed so attn stages its B-operand linearly).
__global__ __launch_bounds__(256) void gemm_mfma(
    const float* __restrict__ x, const float* __restrict__ W,
    ushort* __restrict__ WhT) {
  __shared__ __align__(16) ushort xs[128 * XK];  // 34.8 KB
  __shared__ __align__(16) ushort wt[128 * XK];  // 34.8 KB
  const int bt = blockIdx.x >> 1;
  const int rbase = (blockIdx.x & 1) * 128;
  const int tid = threadIdx.x;
  const int lane = tid & 63;
  const int w = tid >> 6;
  const int wm = w >> 1, wn = w & 1;
  const int la = lane & 15, lg = lane >> 4;

  // stage x (fp32 -> bf16): 16 lanes sweep one row (512B coalesced per group)
  {
    const float* xp = x + ((size_t)bt * NN + rbase) * FF;
    const int r0 = tid >> 4;
    const int c0 = (tid & 15) * 8;
    #pragma unroll
    for (int i = 0; i < 8; ++i) {
      int r = r0 + i * 16;
      float4 v0 = *(const float4*)&xp[r * FF + c0];
      float4 v1 = *(const float4*)&xp[r * FF + c0 + 4];
      uint4 q;
      q.x = pk2(v0.x, v0.y); q.y = pk2(v0.z, v0.w);
      q.z = pk2(v1.x, v1.y); q.w = pk2(v1.z, v1.w);
      *(uint4*)&xs[r * XK + c0] = q;
    }
  }
  // stage W transposed (wt[n][k]), fp32 -> bf16, packed pairs along k
  {
    const int n = tid & 127;
    const int kb = (tid >> 7) * 64;
    #pragma unroll 8
    for (int k2 = 0; k2 < 32; ++k2) {
      int k = kb + k2 * 2;
      float w0 = W[k * FF + n];
      float w1 = W[(k + 1) * FF + n];
      *(uint*)&wt[n * XK + k] = pk2(w0, w1);
    }
  }
  __syncthreads();

  f32x4 acc[4][4] = {};
  #pragma unroll
  for (int ks = 0; ks < 4; ++ks) {
    bf16x8 af[4], bfr[4];
    #pragma unroll
    for (int mi = 0; mi < 4; ++mi)
      af[mi] = *(const bf16x8*)&xs[(wm * 64 + mi * 16 + la) * XK + ks * 32 + lg * 8];
    #pragma unroll
    for (int nt = 0; nt < 4; ++nt)
      bfr[nt] = *(const bf16x8*)&wt[(wn * 64 + nt * 16 + la) * XK + ks * 32 + lg * 8];
    #pragma unroll
    for (int mi = 0; mi < 4; ++mi)
      #pragma unroll
      for (int nt = 0; nt < 4; ++nt)
        acc[mi][nt] = __builtin_amdgcn_mfma_f32_16x16x32_bf16(af[mi], bfr[nt], acc[mi][nt], 0, 0, 0);
  }

  // epilogue: D mapping col=lane&15 (f), row=(lane>>4)*4+reg (node).
  // reg = consecutive nodes -> pack 4 bf16 -> 8B store into WhT[f][n] (32B segments/group)
  ushort* wout = WhT + (size_t)bt * FF * NN;
  #pragma unroll
  for (int mi = 0; mi < 4; ++mi) {
    int n0 = rbase + wm * 64 + mi * 16 + lg * 4;
    #pragma unroll
    for (int nt = 0; nt < 4; ++nt) {
      int f = wn * 64 + nt * 16 + la;
      f32x4 a = acc[mi][nt];
      uint2 pk;
      pk.x = pk2(a[0], a[1]);
      pk.y = pk2(a[2], a[3]);
      *(uint2*)&wout[f * NN + n0] = pk;
    }
  }
}

// Block = (bt, head). 4 waves x 64 query rows. P fragments computed in registers
// (scores are rank-1: e_ij = lrelu(s1_i + s2_j)), PV via MFMA, fused residual+ELU.
__global__ __launch_bounds__(256) void attn_mfma(
    const ushort* __restrict__ WhT, const int* __restrict__ mask,
    const float* __restrict__ av, const float* __restrict__ xres,
    float* __restrict__ xout) {
  __shared__ __align__(16) ushort whT[DD * WTS];  // 16.9 KB: Whh^T [d][j]
  __shared__ __align__(16) float s1s[NN];
  __shared__ __align__(16) float s2s[NN];
  __shared__ __align__(16) float invd[NN];
  __shared__ float redm[4];
  const int bt = blockIdx.x >> 2;
  const int h = blockIdx.x & 3;
  const int tid = threadIdx.x;
  const int lane = tid & 63;
  const int w = tid >> 6;
  const int la = lane & 15, lg = lane >> 4;

  // stage Whh^T rows (straight copy from WhT[bt][h*32+d][:])
  const ushort* wsrc = WhT + ((size_t)bt * FF + h * DD) * NN;
  {
    const int d = tid >> 3;
    const int c8 = tid & 7;
    #pragma unroll
    for (int i = 0; i < 4; ++i) {
      int n0 = (c8 + i * 8) * 8;
      *(uint4*)&whT[d * WTS + n0] = *(const uint4*)&wsrc[d * NN + n0];
    }
  }
  __syncthreads();

  // per-node scores: s1 = Whh[i].a[:32], s2 = Whh[i].a[32:] (column reads, 2-way/free)
  {
    const int i = tid;
    float s1 = 0.f, s2 = 0.f;
    #pragma unroll
    for (int d = 0; d < DD; ++d) {
      float wv = bf2f(whT[d * WTS + i]);
      s1 = fmaf(wv, av[d], s1);
      s2 = fmaf(wv, av[DD + d], s2);
    }
    int mv = mask[bt * NN + i] > 0;
    s1s[i] = s1;
    s2s[i] = mv ? s2 : -1e9f;   // masked j -> exp underflows to exactly 0
    float m = mv ? s2 : -1e30f;
    #pragma unroll
    for (int off = 32; off > 0; off >>= 1) m = fmaxf(m, __shfl_xor(m, off));
    if (lane == 0) redm[w] = m;
  }
  __syncthreads();
  float s2max = fmaxf(fmaxf(redm[0], redm[1]), fmaxf(redm[2], redm[3]));
  s2max = fmaxf(s2max, -1e9f);  // all-masked-slice guard

  // per-lane row constants for the 4 m-tiles (row = w*64 + mi*16 + la)
  float s1r[4], emax[4];
  #pragma unroll
  for (int mi = 0; mi < 4; ++mi) {
    float s1v = s1s[w * 64 + mi * 16 + la];
    s1r[mi] = s1v;
    emax[mi] = lrelu(s1v + s2max);  // exact row max: lrelu monotone, max_j factors
  }

  f32x4 acc[4][2] = {};
  float den[4] = {0.f, 0.f, 0.f, 0.f};
  #pragma unroll
  for (int jc = 0; jc < 4; ++jc) {
    #pragma unroll
    for (int ks = 0; ks < 2; ++ks) {
      const int j0 = jc * 64 + ks * 32 + lg * 8;
      float4 sa = *(const float4*)&s2s[j0];
      float4 sb = *(const float4*)&s2s[j0 + 4];
      bf16x8 b0 = *(const bf16x8*)&whT[la * WTS + j0];
      bf16x8 b1 = *(const bf16x8*)&whT[(16 + la) * WTS + j0];
      #pragma unroll
      for (int mi = 0; mi < 4; ++mi) {
        const float s1v = s1r[mi], em = emax[mi];
        float p0 = __expf(lrelu(s1v + sa.x) - em);
        float p1 = __expf(lrelu(s1v + sa.y) - em);
        float p2 = __expf(lrelu(s1v + sa.z) - em);
        float p3 = __expf(lrelu(s1v + sa.w) - em);
        float p4 = __expf(lrelu(s1v + sb.x) - em);
        float p5 = __expf(lrelu(s1v + sb.y) - em);
        float p6 = __expf(lrelu(s1v + sb.z) - em);
        float p7 = __expf(lrelu(s1v + sb.w) - em);
        den[mi] += ((p0 + p1) + (p2 + p3)) + ((p4 + p5) + (p6 + p7));
        union { uint4 q; bf16x8 v; } u;
        u.q.x = pk2(p0, p1); u.q.y = pk2(p2, p3);
        u.q.z = pk2(p4, p5); u.q.w = pk2(p6, p7);
        acc[mi][0] = __builtin_amdgcn_mfma_f32_16x16x32_bf16(u.v, b0, acc[mi][0], 0, 0, 0);
        acc[mi][1] = __builtin_amdgcn_mfma_f32_16x16x32_bf16(u.v, b1, acc[mi][1], 0, 0, 0);
      }
    }
  }

  // denominator: reduce across the 4 lane-groups sharing row (la), publish 1/den
  #pragma unroll
  for (int mi = 0; mi < 4; ++mi) {
    den[mi] += __shfl_xor(den[mi], 16);
    den[mi] += __shfl_xor(den[mi], 32);
  }
  if (lg == 0) {
    #pragma unroll
    for (int mi = 0; mi < 4; ++mi) {
      int r = w * 64 + mi * 16 + la;
      int mv = mask[bt * NN + r] > 0;
      invd[r] = mv ? 1.f / den[mi] : 0.f;  // den>0 for valid rows (j=r contributes)
    }
  }
  __syncthreads();

  // epilogue: hp = acc*inv; fused residual + ELU. D rows = (lg*4+reg), cols = la+nt*16.
  const float* xr = xres + (size_t)bt * NN * FF + h * DD;
  float* xo = xout + (size_t)bt * NN * FF + h * DD;
  #pragma unroll
  for (int mi = 0; mi < 4; ++mi) {
    f32x4 iv = *(const f32x4*)&invd[w * 64 + mi * 16 + lg * 4];
    #pragma unroll
    for (int reg = 0; reg < 4; ++reg) {
      int r = w * 64 + mi * 16 + lg * 4 + reg;
      #pragma unroll
      for (int nt = 0; nt < 2; ++nt) {
        int d = nt * 16 + la;
        float o = elu1(xr[(size_t)r * FF + d] + acc[mi][nt][reg] * iv[reg]);
        xo[(size_t)r * FF + d] = o;
      }
    }
  }
}

// 8 rows/block: half-wave (32 lanes) per row, float4 per lane.
__global__ __launch_bounds__(256) void layernorm_mask(
    const float* __restrict__ x, const int* __restrict__ mask,
    const float* __restrict__ gamma, const float* __restrict__ beta,
    float* __restrict__ out) {
  const int l32 = threadIdx.x & 31;
  const size_t row = (size_t)blockIdx.x * 8 + (threadIdx.x >> 5);
  float4 v = *(const float4*)&x[row * FF + l32 * 4];
  float sum = v.x + v.y + v.z + v.w;
  float sq = v.x * v.x + v.y * v.y + v.z * v.z + v.w * v.w;
  #pragma unroll
  for (int off = 16; off > 0; off >>= 1) {
    sum += __shfl_xor(sum, off);
    sq += __shfl_xor(sq, off);
  }
  const float mu = sum * (1.f / FF);
  const float var = sq * (1.f / FF) - mu * mu;
  const float rstd = rsqrtf(var + 1e-5f);
  const float m = mask[row] > 0 ? 1.f : 0.f;
  float4 g = *(const float4*)&gamma[l32 * 4];
  float4 b = *(const float4*)&beta[l32 * 4];
  float4 o;
  o.x = ((v.x - mu) * rstd * g.x + b.x) * m;
  o.y = ((v.y - mu) * rstd * g.y + b.y) * m;
  o.z = ((v.z - mu) * rstd * g.z + b.z) * m;
  o.w = ((v.w - mu) * rstd * g.w + b.w) * m;
  *(float4*)&out[row * FF + l32 * 4] = o;
}

extern "C" void kernel_launch(void* const* d_in, const int* in_sizes, int n_in,
                              void* d_out, int out_size, void* d_ws, size_t ws_size,
                              hipStream_t stream) {
  const float* xin   = (const float*)d_in[0];
  const int*   mask  = (const int*)d_in[1];
  const float* W0    = (const float*)d_in[2];
  const float* a0    = (const float*)d_in[3];
  const float* W1    = (const float*)d_in[4];
  const float* a1    = (const float*)d_in[5];
  const float* gamma = (const float*)d_in[6];
  const float* beta  = (const float*)d_in[7];

  float*  x_cur = (float*)d_ws;                       // 16.78 MB
  ushort* WhT   = (ushort*)(x_cur + (size_t)BT * NN * FF);  // 8.39 MB

  gemm_mfma<<<BT * 2, 256, 0, stream>>>(xin, W0, WhT);
  attn_mfma<<<BT * HH, 256, 0, stream>>>(WhT, mask, a0, xin, x_cur);
  gemm_mfma<<<BT * 2, 256, 0, stream>>>(x_cur, W1, WhT);
  attn_mfma<<<BT * HH, 256, 0, stream>>>(WhT, mask, a1, x_cur, x_cur);
  layernorm_mask<<<BT * NN / 8, 256, 0, stream>>>(x_cur, mask, gamma, beta, (float*)d_out);
}

// Round 3
// 55.986 us; speedup vs baseline: 3.0555x; 1.3124x over previous
//
#include <hip/hip_runtime.h>
#include <hip/hip_bf16.h>

#define BT 128   // B*T
#define NN 256   // nodes
#define FF 128   // features
#define HH 4     // heads
#define DD 32    // head dim
#define XK 136   // LDS k-stride (bf16): 272B, 16B-aligned, spreads 8 bank-groups
#define WTS 264  // LDS j-stride (bf16) for whT: 528B
#define L2E 1.4426950408889634f

typedef __attribute__((ext_vector_type(8))) short bf16x8;
typedef __attribute__((ext_vector_type(4))) float f32x4;
typedef unsigned int uint;
typedef unsigned short ushort;

__device__ __forceinline__ float elu1(float x) { return x > 0.f ? x : (__expf(x) - 1.f); }
__device__ __forceinline__ float exp2_fast(float x) {
  float r; asm("v_exp_f32 %0, %1" : "=v"(r) : "v"(x)); return r;
}
__device__ __forceinline__ ushort f2bfn(float f) {
  __hip_bfloat16 h = __float2bfloat16(f);
  return *reinterpret_cast<ushort*>(&h);
}
__device__ __forceinline__ uint pk2(float a, float b) {  // compiler -> v_cvt_pk_bf16_f32
  return (uint)f2bfn(a) | ((uint)f2bfn(b) << 16);
}

// Block = (bt, 64-row tile). 4 waves: wm=w>>1 (32-row), wn=w&1 (64-col). 512 blocks, 2/CU.
// A source: fp32 (layer 0) or bf16 (layer 1). Output WhT[bt][f][n] bf16.
template<bool ABF>
__global__ __launch_bounds__(256) void gemm_mfma(
    const void* __restrict__ xv, const float* __restrict__ W,
    ushort* __restrict__ WhT) {
  __shared__ __align__(16) ushort xs[64 * XK];   // 17.4 KB
  __shared__ __align__(16) ushort wt[128 * XK];  // 34.8 KB
  const int bt = blockIdx.x >> 2;
  const int rbase = (blockIdx.x & 3) * 64;
  const int tid = threadIdx.x;
  const int lane = tid & 63;
  const int w = tid >> 6;
  const int wm = w >> 1, wn = w & 1;
  const int la = lane & 15, lg = lane >> 4;

  // stage x tile (64 rows x 128 cols)
  {
    const int r0 = tid >> 4;
    const int c0 = (tid & 15) * 8;
    if (ABF) {
      const ushort* xp = (const ushort*)xv + ((size_t)bt * NN + rbase) * FF;
      #pragma unroll
      for (int i = 0; i < 4; ++i) {
        int r = r0 + i * 16;
        *(uint4*)&xs[r * XK + c0] = *(const uint4*)&xp[(size_t)r * FF + c0];
      }
    } else {
      const float* xp = (const float*)xv + ((size_t)bt * NN + rbase) * FF;
      #pragma unroll
      for (int i = 0; i < 4; ++i) {
        int r = r0 + i * 16;
        float4 v0 = *(const float4*)&xp[(size_t)r * FF + c0];
        float4 v1 = *(const float4*)&xp[(size_t)r * FF + c0 + 4];
        uint4 q;
        q.x = pk2(v0.x, v0.y); q.y = pk2(v0.z, v0.w);
        q.z = pk2(v1.x, v1.y); q.w = pk2(v1.z, v1.w);
        *(uint4*)&xs[r * XK + c0] = q;
      }
    }
  }
  // stage W transposed: wt[n][k], packed k-pairs
  {
    const int n = tid & 127;
    const int kb = (tid >> 7) * 64;
    #pragma unroll 8
    for (int k2 = 0; k2 < 32; ++k2) {
      int k = kb + k2 * 2;
      *(uint*)&wt[n * XK + k] = pk2(W[k * FF + n], W[(k + 1) * FF + n]);
    }
  }
  __syncthreads();

  f32x4 acc[2][4] = {};
  #pragma unroll
  for (int ks = 0; ks < 4; ++ks) {
    bf16x8 af[2], bfr[4];
    #pragma unroll
    for (int mi = 0; mi < 2; ++mi)
      af[mi] = *(const bf16x8*)&xs[(wm * 32 + mi * 16 + la) * XK + ks * 32 + lg * 8];
    #pragma unroll
    for (int nt = 0; nt < 4; ++nt)
      bfr[nt] = *(const bf16x8*)&wt[(wn * 64 + nt * 16 + la) * XK + ks * 32 + lg * 8];
    #pragma unroll
    for (int mi = 0; mi < 2; ++mi)
      #pragma unroll
      for (int nt = 0; nt < 4; ++nt)
        acc[mi][nt] = __builtin_amdgcn_mfma_f32_16x16x32_bf16(af[mi], bfr[nt], acc[mi][nt], 0, 0, 0);
  }

  // epilogue: D col=la (f), row=lg*4+reg (node). 4 consecutive nodes -> 8B store.
  ushort* wout = WhT + (size_t)bt * FF * NN;
  #pragma unroll
  for (int mi = 0; mi < 2; ++mi) {
    int n0 = rbase + wm * 32 + mi * 16 + lg * 4;
    #pragma unroll
    for (int nt = 0; nt < 4; ++nt) {
      int f = wn * 64 + nt * 16 + la;
      f32x4 a = acc[mi][nt];
      uint2 pk;
      pk.x = pk2(a[0], a[1]);
      pk.y = pk2(a[2], a[3]);
      *(uint2*)&wout[f * NN + n0] = pk;
    }
  }
}

// Block = (bt, head). 4 waves x 64 query rows. Valid-j compaction; base-2 softmax;
// rank-1 scores -> P fragments in registers; PV via MFMA; fused residual+ELU.
template<bool WRITE_BF>
__global__ __launch_bounds__(256) void attn_mfma(
    const ushort* __restrict__ WhT, const int* __restrict__ mask,
    const float* __restrict__ av, const float* __restrict__ xres,
    float* __restrict__ xout, ushort* __restrict__ xbf) {
  __shared__ __align__(16) ushort whT[DD * WTS];   // original [d][j], 16.9 KB
  __shared__ __align__(16) ushort whTc[DD * WTS];  // compacted [d][jc], 16.9 KB
  __shared__ __align__(16) float s2c[NN];          // compacted scaled s2
  __shared__ float s2all[NN];
  __shared__ float s1s[NN];
  __shared__ float invd[NN];
  __shared__ int jmap[NN];
  __shared__ int validr[NN];
  __shared__ float redm[4];
  __shared__ int wcnt[4];
  const int bt = blockIdx.x >> 2;
  const int h = blockIdx.x & 3;
  const int tid = threadIdx.x;
  const int lane = tid & 63;
  const int w = tid >> 6;
  const int la = lane & 15, lg = lane >> 4;

  // stage Whh^T rows (straight copy)
  const ushort* wsrc = WhT + ((size_t)bt * FF + h * DD) * NN;
  {
    const int d = tid >> 3;
    const int c8 = tid & 7;
    #pragma unroll
    for (int i = 0; i < 4; ++i) {
      int n0 = (c8 + i * 8) * 8;
      *(uint4*)&whT[d * WTS + n0] = *(const uint4*)&wsrc[d * NN + n0];
    }
  }
  __syncthreads();

  // per-node scores (scaled by log2 e), mask, wave-max, ballot compaction indices
  {
    const int i = tid;
    float s1 = 0.f, s2 = 0.f;
    #pragma unroll
    for (int d = 0; d < DD; ++d) {
      float wv = __bfloat162float(*(const __hip_bfloat16*)&whT[d * WTS + i]);
      s1 = fmaf(wv, av[d], s1);
      s2 = fmaf(wv, av[DD + d], s2);
    }
    int mv = mask[bt * NN + i] > 0;
    validr[i] = mv;
    s1s[i] = s1 * L2E;
    s2all[i] = s2 * L2E;
    float m = mv ? s2 * L2E : -1e30f;
    #pragma unroll
    for (int off = 32; off > 0; off >>= 1) m = fmaxf(m, __shfl_xor(m, off));
    unsigned long long bal = __ballot(mv);
    if (lane == 0) { redm[w] = m; wcnt[w] = __popcll(bal); }
    __syncthreads();
    if (mv) {
      int base = 0;
      #pragma unroll
      for (int ww = 0; ww < 4; ++ww) if (ww < w) base += wcnt[ww];
      jmap[base + __popcll(bal & ((1ull << lane) - 1ull))] = i;
    }
  }
  __syncthreads();
  const int jv = wcnt[0] + wcnt[1] + wcnt[2] + wcnt[3];
  const int jvpad = (jv + 63) & ~63;
  const float s2max = fmaxf(fmaxf(redm[0], redm[1]), fmaxf(redm[2], redm[3]));

  // compact columns: thread owns col tid; pad cols zeroed (p=0 there, 0x0=0 safe)
  {
    const int c = tid;
    if (c < jv) {
      int jsrc = jmap[c];
      s2c[c] = s2all[jsrc];
      #pragma unroll
      for (int d = 0; d < DD; ++d) whTc[d * WTS + c] = whT[d * WTS + jsrc];
    } else {
      s2c[c] = -2e9f;
      #pragma unroll
      for (int d = 0; d < DD; ++d) whTc[d * WTS + c] = 0;
    }
  }
  __syncthreads();

  // per-lane row constants (scaled space): em = max(t, 0.2t), t = s1' + s2max'
  float s1r[4], em[4];
  #pragma unroll
  for (int mi = 0; mi < 4; ++mi) {
    float s1v = s1s[w * 64 + mi * 16 + la];
    s1r[mi] = s1v;
    float t = s1v + s2max;
    em[mi] = fmaxf(t, 0.2f * t);
  }

  f32x4 acc[4][2] = {};
  float den[4] = {0.f, 0.f, 0.f, 0.f};
  for (int j0b = 0; j0b < jvpad; j0b += 64) {
    #pragma unroll
    for (int ks = 0; ks < 2; ++ks) {
      const int j0 = j0b + ks * 32 + lg * 8;
      float4 sa = *(const float4*)&s2c[j0];
      float4 sb = *(const float4*)&s2c[j0 + 4];
      bf16x8 b0 = *(const bf16x8*)&whTc[la * WTS + j0];
      bf16x8 b1 = *(const bf16x8*)&whTc[(16 + la) * WTS + j0];
      #pragma unroll
      for (int mi = 0; mi < 4; ++mi) {
        const float s1v = s1r[mi], emv = em[mi];
        float t0 = s1v + sa.x, t1 = s1v + sa.y, t2 = s1v + sa.z, t3 = s1v + sa.w;
        float t4 = s1v + sb.x, t5 = s1v + sb.y, t6 = s1v + sb.z, t7 = s1v + sb.w;
        float p0 = exp2_fast(fmaxf(t0, 0.2f * t0) - emv);
        float p1 = exp2_fast(fmaxf(t1, 0.2f * t1) - emv);
        float p2 = exp2_fast(fmaxf(t2, 0.2f * t2) - emv);
        float p3 = exp2_fast(fmaxf(t3, 0.2f * t3) - emv);
        float p4 = exp2_fast(fmaxf(t4, 0.2f * t4) - emv);
        float p5 = exp2_fast(fmaxf(t5, 0.2f * t5) - emv);
        float p6 = exp2_fast(fmaxf(t6, 0.2f * t6) - emv);
        float p7 = exp2_fast(fmaxf(t7, 0.2f * t7) - emv);
        den[mi] += ((p0 + p1) + (p2 + p3)) + ((p4 + p5) + (p6 + p7));
        union { uint4 q; bf16x8 v; } u;
        u.q.x = pk2(p0, p1); u.q.y = pk2(p2, p3);
        u.q.z = pk2(p4, p5); u.q.w = pk2(p6, p7);
        acc[mi][0] = __builtin_amdgcn_mfma_f32_16x16x32_bf16(u.v, b0, acc[mi][0], 0, 0, 0);
        acc[mi][1] = __builtin_amdgcn_mfma_f32_16x16x32_bf16(u.v, b1, acc[mi][1], 0, 0, 0);
      }
    }
  }

  // denominator: reduce the 4 k-groups per row, publish 1/den (0 for masked rows)
  #pragma unroll
  for (int mi = 0; mi < 4; ++mi) {
    den[mi] += __shfl_xor(den[mi], 16);
    den[mi] += __shfl_xor(den[mi], 32);
  }
  if (lg == 0) {
    #pragma unroll
    for (int mi = 0; mi < 4; ++mi) {
      int r = w * 64 + mi * 16 + la;
      invd[r] = validr[r] ? 1.f / den[mi] : 0.f;  // valid row => den >= 1
    }
  }
  __syncthreads();

  // epilogue: residual + ELU; optional bf16 copy for next layer's GEMM
  const float* xr = xres + (size_t)bt * NN * FF + h * DD;
  float* xo = xout + (size_t)bt * NN * FF + h * DD;
  ushort* xb = WRITE_BF ? xbf + (size_t)bt * NN * FF + h * DD : nullptr;
  #pragma unroll
  for (int mi = 0; mi < 4; ++mi) {
    f32x4 iv = *(const f32x4*)&invd[w * 64 + mi * 16 + lg * 4];
    #pragma unroll
    for (int reg = 0; reg < 4; ++reg) {
      int r = w * 64 + mi * 16 + lg * 4 + reg;
      #pragma unroll
      for (int nt = 0; nt < 2; ++nt) {
        int d = nt * 16 + la;
        float o = elu1(xr[(size_t)r * FF + d] + acc[mi][nt][reg] * iv[reg]);
        xo[(size_t)r * FF + d] = o;
        if (WRITE_BF) xb[(size_t)r * FF + d] = f2bfn(o);
      }
    }
  }
}

// 8 rows/block: 32 lanes per row, float4 per lane.
__global__ __launch_bounds__(256) void layernorm_mask(
    const float* __restrict__ x, const int* __restrict__ mask,
    const float* __restrict__ gamma, const float* __restrict__ beta,
    float* __restrict__ out) {
  const int l32 = threadIdx.x & 31;
  const size_t row = (size_t)blockIdx.x * 8 + (threadIdx.x >> 5);
  float4 v = *(const float4*)&x[row * FF + l32 * 4];
  float sum = v.x + v.y + v.z + v.w;
  float sq = v.x * v.x + v.y * v.y + v.z * v.z + v.w * v.w;
  #pragma unroll
  for (int off = 16; off > 0; off >>= 1) {
    sum += __shfl_xor(sum, off);
    sq += __shfl_xor(sq, off);
  }
  const float mu = sum * (1.f / FF);
  const float var = sq * (1.f / FF) - mu * mu;
  const float rstd = rsqrtf(var + 1e-5f);
  const float m = mask[row] > 0 ? 1.f : 0.f;
  float4 g = *(const float4*)&gamma[l32 * 4];
  float4 b = *(const float4*)&beta[l32 * 4];
  float4 o;
  o.x = ((v.x - mu) * rstd * g.x + b.x) * m;
  o.y = ((v.y - mu) * rstd * g.y + b.y) * m;
  o.z = ((v.z - mu) * rstd * g.z + b.z) * m;
  o.w = ((v.w - mu) * rstd * g.w + b.w) * m;
  *(float4*)&out[row * FF + l32 * 4] = o;
}

extern "C" void kernel_launch(void* const* d_in, const int* in_sizes, int n_in,
                              void* d_out, int out_size, void* d_ws, size_t ws_size,
                              hipStream_t stream) {
  const float* xin   = (const float*)d_in[0];
  const int*   mask  = (const int*)d_in[1];
  const float* W0    = (const float*)d_in[2];
  const float* a0    = (const float*)d_in[3];
  const float* W1    = (const float*)d_in[4];
  const float* a1    = (const float*)d_in[5];
  const float* gamma = (const float*)d_in[6];
  const float* beta  = (const float*)d_in[7];

  float*  x_cur = (float*)d_ws;                              // 16.78 MB
  ushort* WhT   = (ushort*)(x_cur + (size_t)BT * NN * FF);   // 8.39 MB
  ushort* xbf   = WhT + (size_t)BT * FF * NN;                // 8.39 MB

  gemm_mfma<false><<<BT * 4, 256, 0, stream>>>(xin, W0, WhT);
  attn_mfma<true><<<BT * HH, 256, 0, stream>>>(WhT, mask, a0, xin, x_cur, xbf);
  gemm_mfma<true><<<BT * 4, 256, 0, stream>>>(xbf, W1, WhT);
  attn_mfma<false><<<BT * HH, 256, 0, stream>>>(WhT, mask, a1, x_cur, x_cur, nullptr);
  layernorm_mask<<<BT * NN / 8, 256, 0, stream>>>(x_cur, mask, gamma, beta, (float*)d_out);
}